// Round 9
// baseline (1435.902 us; speedup 1.0000x reference)
//
#include <hip/hip_runtime.h>
#include <hip/hip_bf16.h>

typedef __bf16 bf16_t;
typedef __bf16 bf16x8 __attribute__((ext_vector_type(8)));
typedef float  f32x4  __attribute__((ext_vector_type(4)));
typedef int    i32x4  __attribute__((ext_vector_type(4)));

static constexpr int M_ = 8192;   // 4 * 2048
static constexpr int N_ = 4096;   // out_f
static constexpr int K_ = 4096;   // in_f

// GEMM geometry: 256x512 block, BK=32, 8 waves (2M x 4N) of 128x128 each.
static constexpr int BM = 256, BN = 512, BK = 32;
static constexpr int NT = K_ / BK;        // 128 K-tiles
static constexpr int A_ELEMS = BM * BK;   // 8192  (16 KB)
static constexpr int B_ELEMS = BN * BK;   // 16384 (32 KB)

// async global->LDS, 16B per lane. LDS dest must be wave-uniform base + lane*16.
__device__ __forceinline__ void load_lds16(const bf16_t* g, bf16_t* l) {
  __builtin_amdgcn_global_load_lds(
      (const __attribute__((address_space(1))) void*)g,
      (__attribute__((address_space(3))) void*)l,
      16, 0, 0);
}

#define MFMA16(a, b, c) __builtin_amdgcn_mfma_f32_16x16x32_bf16((a), (b), (c), 0, 0, 0)

// ---- pass 1: x fp32 -> bf16 (nt loads: read-once) -------------------------
__global__ __launch_bounds__(256) void cvt_x_kernel(const float* __restrict__ x,
                                                    bf16_t* __restrict__ xb) {
  const size_t i = ((size_t)blockIdx.x * 256 + threadIdx.x) * 8;
  const f32x4 f0 = __builtin_nontemporal_load((const f32x4*)(x + i));
  const f32x4 f1 = __builtin_nontemporal_load((const f32x4*)(x + i + 4));
  bf16x8 o;
  o[0] = (bf16_t)f0[0]; o[1] = (bf16_t)f0[1]; o[2] = (bf16_t)f0[2]; o[3] = (bf16_t)f0[3];
  o[4] = (bf16_t)f1[0]; o[5] = (bf16_t)f1[1]; o[6] = (bf16_t)f1[2]; o[7] = (bf16_t)f1[3];
  *(bf16x8*)(xb + i) = o;   // cached store: gemm re-reads this soon
}

// ---- pass 2: W[o][i] = q[o][i] * scales[o][i/128] -> bf16 ----------------
__global__ __launch_bounds__(256) void dequant_kernel(const int* __restrict__ q,
                                                      const float* __restrict__ s,
                                                      bf16_t* __restrict__ wb) {
  const size_t base = ((size_t)blockIdx.x * 256 + threadIdx.x) * 8;
  const int o  = (int)(base >> 12);
  const int ii = (int)(base & 4095);
  const float sc = s[(o << 5) + (ii >> 7)];
  const i32x4 q0 = __builtin_nontemporal_load((const i32x4*)(q + base));
  const i32x4 q1 = __builtin_nontemporal_load((const i32x4*)(q + base + 4));
  bf16x8 w;
  w[0] = (bf16_t)((float)q0[0] * sc); w[1] = (bf16_t)((float)q0[1] * sc);
  w[2] = (bf16_t)((float)q0[2] * sc); w[3] = (bf16_t)((float)q0[3] * sc);
  w[4] = (bf16_t)((float)q1[0] * sc); w[5] = (bf16_t)((float)q1[1] * sc);
  w[6] = (bf16_t)((float)q1[2] * sc); w[7] = (bf16_t)((float)q1[3] * sc);
  *(bf16x8*)(wb + base) = w;  // cached store: gemm re-reads this soon
}

// ---- pass 3: C = A . B^T + bias ------------------------------------------
// 256x512 block, BK=32, wave tile 128x128 (acc 8x8 f32x4 = 256 VGPR).
// Per CU per K-tile: 128 ds_read_b128 vs 2483 MFMA cyc -> MFMA-dominant.
// Swizzle (64-B rows): logical k-group kg lives at phys slot
// kg ^ (row&3) ^ ((row>>2)&3) -> verified 2-way (free) bank pattern.
// Phases: P1 reads af0-3+bq0-3 (8, consumption-ordered), P2 bq4-7 (4),
// P3 af4-7 (4) + stage B[T+2], P4 none + stage A[T+2] + vmcnt(6).
// One barrier per phase; lgkm(0) before each closing barrier certifies this
// wave's reads before anyone restages that region.
// Grid 32x8 = 256 blocks = 1/CU; bn = (bid&7)*512: each XCD's 32 CUs share
// one 4-MiB B panel (= its L2), A read once per block.
__global__ __launch_bounds__(512, 2) void gemm_kernel(const bf16_t* __restrict__ A,
                                                      const bf16_t* __restrict__ B,
                                                      const float* __restrict__ bias,
                                                      float* __restrict__ C) {
  __shared__ __align__(16) bf16_t As[2 * A_ELEMS];  // 32 KiB
  __shared__ __align__(16) bf16_t Bs[2 * B_ELEMS];  // 64 KiB

  const int tid  = threadIdx.x;
  const int lane = tid & 63;
  const int wave = tid >> 6;
  const int ln = lane & 15;
  const int lq = lane >> 4;
  const int wm = wave >> 2;   // 0..1 : 128-row half
  const int wn = wave & 3;    // 0..3 : 128-col quarter

  const int bid = blockIdx.x;
  const int bn  = (bid & 7) * BN;   // XCD-id * 512: per-XCD B panel
  const int bm  = (bid >> 3) * BM;

  // staging: thread t covers row (t>>2) of a 128-row chunk, 16B at
  // inverse-swizzled col-group (t&3) ^ swz(row), swz = (r&3)^((r>>2)&3).
  const int r_sub  = tid >> 2;                               // 0..127
  const int swz_r  = ((tid >> 2) & 3) ^ ((tid >> 4) & 3);
  const int g_col  = (((tid & 3) ^ swz_r) * 8);
  const size_t a_base = (size_t)(bm + r_sub) * K_ + g_col;
  const size_t b_base = (size_t)(bn + r_sub) * K_ + g_col;
  const int lds_off = tid * 8;

  auto stageA = [&](int t) {      // 2 x 128-row chunks
#pragma unroll
    for (int c = 0; c < 2; ++c)
      load_lds16(A + a_base + (size_t)c * 128 * K_ + (size_t)t * BK,
                 As + (t & 1) * A_ELEMS + c * 4096 + lds_off);
  };
  auto stageB = [&](int t) {      // 4 x 128-row chunks
#pragma unroll
    for (int c = 0; c < 4; ++c)
      load_lds16(B + b_base + (size_t)c * 128 * K_ + (size_t)t * BK,
                 Bs + (t & 1) * B_ELEMS + c * 4096 + lds_off);
  };

  // ds_read: row = base16 + ln, phys slot = lq ^ (ln&3) ^ ((ln>>2)&3)
  const int kx = ((lq ^ (ln & 3) ^ ((ln >> 2) & 3)) * 8);
  const int a_row = (wm * 128 + ln) * BK + kx;   // + i*16*BK = i*512
  const int b_row = (wn * 128 + ln) * BK + kx;   // + j*512

  f32x4 acc[8][8] = {};

  // prologue: B0,A0,B1,A1 (12 loads); retire tile0's 6, keep tile1's 6 in flight.
  stageB(0); stageA(0); stageB(1); stageA(1);
  asm volatile("s_waitcnt vmcnt(6)" ::: "memory");
  __builtin_amdgcn_s_barrier();

  for (int T = 0; T < NT; ++T) {
    const bf16_t* as = As + (T & 1) * A_ELEMS;
    const bf16_t* bs = Bs + (T & 1) * B_ELEMS;
    bf16x8 af[8], bq[8];

    // ---- P1: reads af0 bq0-3 af1-3 (consumption order); mfma i0-3 x j0-3
    af[0] = *(const bf16x8*)(as + a_row);
#pragma unroll
    for (int j = 0; j < 4; ++j)
      bq[j] = *(const bf16x8*)(bs + b_row + j * 512);
#pragma unroll
    for (int i = 1; i < 4; ++i)
      af[i] = *(const bf16x8*)(as + a_row + i * 512);
    __builtin_amdgcn_s_setprio(1);
#pragma unroll
    for (int i = 0; i < 4; ++i)
#pragma unroll
      for (int j = 0; j < 4; ++j)
        acc[i][j] = MFMA16(af[i], bq[j], acc[i][j]);
    __builtin_amdgcn_s_setprio(0);
    asm volatile("s_waitcnt lgkmcnt(0)" ::: "memory");
    __builtin_amdgcn_s_barrier();

    // ---- P2: reads bq4-7; mfma i0-3 x j4-7
#pragma unroll
    for (int j = 4; j < 8; ++j)
      bq[j] = *(const bf16x8*)(bs + b_row + j * 512);
    __builtin_amdgcn_s_setprio(1);
#pragma unroll
    for (int i = 0; i < 4; ++i)
#pragma unroll
      for (int j = 4; j < 8; ++j)
        acc[i][j] = MFMA16(af[i], bq[j], acc[i][j]);
    __builtin_amdgcn_s_setprio(0);
    asm volatile("s_waitcnt lgkmcnt(0)" ::: "memory");
    __builtin_amdgcn_s_barrier();

    // ---- P3: reads af4-7; stage B[T+2] (B reads done at P2 close); mfma i4-7 x j4-7
#pragma unroll
    for (int i = 4; i < 8; ++i)
      af[i] = *(const bf16x8*)(as + a_row + i * 512);
    if (T + 2 < NT) stageB(T + 2);
    __builtin_amdgcn_s_setprio(1);
#pragma unroll
    for (int i = 4; i < 8; ++i)
#pragma unroll
      for (int j = 4; j < 8; ++j)
        acc[i][j] = MFMA16(af[i], bq[j], acc[i][j]);
    __builtin_amdgcn_s_setprio(0);
    asm volatile("s_waitcnt lgkmcnt(0)" ::: "memory");
    __builtin_amdgcn_s_barrier();

    // ---- P4: no reads; stage A[T+2] (A reads done at P3 close); mfma i4-7 x j0-3;
    //      boundary counted wait: retire tile T+1's 6, keep T+2's 6 in flight.
    if (T + 2 < NT) stageA(T + 2);
    __builtin_amdgcn_s_setprio(1);
#pragma unroll
    for (int i = 4; i < 8; ++i)
#pragma unroll
      for (int j = 0; j < 4; ++j)
        acc[i][j] = MFMA16(af[i], bq[j], acc[i][j]);
    __builtin_amdgcn_s_setprio(0);
    if (T + 2 < NT) {
      asm volatile("s_waitcnt vmcnt(6)" ::: "memory");
    } else {
      asm volatile("s_waitcnt vmcnt(0)" ::: "memory");
    }
    __builtin_amdgcn_s_barrier();
  }

  // epilogue: C/D layout col=lane&15, row=(lane>>4)*4+reg  [m89/m91 verified]
  // nt stores: C is write-once.
#pragma unroll
  for (int j = 0; j < 8; ++j) {
    const int col = bn + wn * 128 + j * 16 + ln;
    const float bv = bias[col];
#pragma unroll
    for (int i = 0; i < 8; ++i) {
      const int row0 = bm + wm * 128 + i * 16 + lq * 4;
      float* cp = C + (size_t)row0 * N_ + col;
#pragma unroll
      for (int r = 0; r < 4; ++r) {
        __builtin_nontemporal_store(acc[i][j][r] + bv, cp);
        cp += N_;
      }
    }
  }
}

extern "C" void kernel_launch(void* const* d_in, const int* in_sizes, int n_in,
                              void* d_out, int out_size, void* d_ws, size_t ws_size,
                              hipStream_t stream) {
  const float* x    = (const float*)d_in[0];  // [4,2048,4096] fp32
  const int*   qw   = (const int*)d_in[1];    // [4096,4096] int32 in [0,16)
  const float* sc   = (const float*)d_in[2];  // [4096,32] fp32
  const float* bias = (const float*)d_in[3];  // [4096] fp32
  float* out = (float*)d_out;                 // [8192,4096] fp32

  bf16_t* xb = (bf16_t*)d_ws;                 // M_*K_ bf16 = 64 MiB
  bf16_t* wb = xb + (size_t)M_ * K_;          // N_*K_ bf16 = 32 MiB

  cvt_x_kernel<<<(int)(((size_t)M_ * K_) / (256 * 8)), 256, 0, stream>>>(x, xb);
  dequant_kernel<<<(int)(((size_t)N_ * K_) / (256 * 8)), 256, 0, stream>>>(qw, sc, wb);

  const int nwg = (M_ / BM) * (N_ / BN);  // 32 * 8 = 256 blocks, 1 per CU
  gemm_kernel<<<nwg, 512, 0, stream>>>(xb, wb, bias, out);
}

// Round 10
// 555.686 us; speedup vs baseline: 2.5840x; 2.5840x over previous
//
#include <hip/hip_runtime.h>
#include <hip/hip_bf16.h>

typedef __bf16 bf16_t;
typedef __bf16 bf16x8 __attribute__((ext_vector_type(8)));
typedef float  f32x4  __attribute__((ext_vector_type(4)));
typedef int    i32x4  __attribute__((ext_vector_type(4)));

static constexpr int M_ = 8192;   // 4 * 2048
static constexpr int N_ = 4096;   // out_f
static constexpr int K_ = 4096;   // in_f

// GEMM geometry: 256x128 block, BK=32, 4 waves (2M x 2N) of 128x64 each.
// Triple-buffered LDS (72 KB) -> 2 blocks/CU: two INDEPENDENT barrier groups
// per CU so one block's MFMA overlaps the other's LDS/stage phases (m114).
static constexpr int BM = 256, BN = 128, BK = 32;
static constexpr int NT = K_ / BK;          // 128 K-tiles
static constexpr int A_T = BM * BK;         // 8192 elems (16 KB)
static constexpr int B_T = BN * BK;         // 4096 elems (8 KB)

// async global->LDS, 16B per lane. LDS dest must be wave-uniform base + lane*16.
__device__ __forceinline__ void load_lds16(const bf16_t* g, bf16_t* l) {
  __builtin_amdgcn_global_load_lds(
      (const __attribute__((address_space(1))) void*)g,
      (__attribute__((address_space(3))) void*)l,
      16, 0, 0);
}

#define MFMA16(a, b, c) __builtin_amdgcn_mfma_f32_16x16x32_bf16((a), (b), (c), 0, 0, 0)

// ---- pass 1: x fp32 -> bf16 (nt loads: read-once) -------------------------
__global__ __launch_bounds__(256) void cvt_x_kernel(const float* __restrict__ x,
                                                    bf16_t* __restrict__ xb) {
  const size_t i = ((size_t)blockIdx.x * 256 + threadIdx.x) * 8;
  const f32x4 f0 = __builtin_nontemporal_load((const f32x4*)(x + i));
  const f32x4 f1 = __builtin_nontemporal_load((const f32x4*)(x + i + 4));
  bf16x8 o;
  o[0] = (bf16_t)f0[0]; o[1] = (bf16_t)f0[1]; o[2] = (bf16_t)f0[2]; o[3] = (bf16_t)f0[3];
  o[4] = (bf16_t)f1[0]; o[5] = (bf16_t)f1[1]; o[6] = (bf16_t)f1[2]; o[7] = (bf16_t)f1[3];
  *(bf16x8*)(xb + i) = o;   // cached store: gemm re-reads this soon
}

// ---- pass 2: W[o][i] = q[o][i] * scales[o][i/128] -> bf16 ----------------
__global__ __launch_bounds__(256) void dequant_kernel(const int* __restrict__ q,
                                                      const float* __restrict__ s,
                                                      bf16_t* __restrict__ wb) {
  const size_t base = ((size_t)blockIdx.x * 256 + threadIdx.x) * 8;
  const int o  = (int)(base >> 12);
  const int ii = (int)(base & 4095);
  const float sc = s[(o << 5) + (ii >> 7)];
  const i32x4 q0 = __builtin_nontemporal_load((const i32x4*)(q + base));
  const i32x4 q1 = __builtin_nontemporal_load((const i32x4*)(q + base + 4));
  bf16x8 w;
  w[0] = (bf16_t)((float)q0[0] * sc); w[1] = (bf16_t)((float)q0[1] * sc);
  w[2] = (bf16_t)((float)q0[2] * sc); w[3] = (bf16_t)((float)q0[3] * sc);
  w[4] = (bf16_t)((float)q1[0] * sc); w[5] = (bf16_t)((float)q1[1] * sc);
  w[6] = (bf16_t)((float)q1[2] * sc); w[7] = (bf16_t)((float)q1[3] * sc);
  *(bf16x8*)(wb + base) = w;  // cached store: gemm re-reads this soon
}

// ---- pass 3: C = A . B^T + bias ------------------------------------------
// LDS layout per operand tile (rows R, BK=32): row-pairs packed into 128-B
// lds-rows. Logical (m, k): elem = (m>>1)*64 + S*8 + (k&7),
//   S = ((m&1)*4 + (k>>3)) ^ ((m>>1)&7).
// Quarter-wave (16 lanes, fixed lq) hits 8 phys slots x2 = 2-way = free.
// Staging (global_load_lds writes linear tid*16B): thread t supplies the
// global element that belongs at its phys slot (inverse map, rule #21).
// Main loop (single phase / K-tile): ds_reads (consumption order) ->
// stage T+2 into third buffer -> 32 MFMA (compiler's fine-grained lgkm) ->
// vmcnt(6) retiring T+1 -> lgkm(0) -> barrier -> rotate buffers.
__global__ __launch_bounds__(256, 2) void gemm_kernel(const bf16_t* __restrict__ A,
                                                      const bf16_t* __restrict__ B,
                                                      const float* __restrict__ bias,
                                                      float* __restrict__ C) {
  __shared__ __align__(16) bf16_t As[3 * A_T];  // 48 KiB
  __shared__ __align__(16) bf16_t Bs[3 * B_T];  // 24 KiB

  const int tid  = threadIdx.x;
  const int lane = tid & 63;
  const int wave = tid >> 6;   // 0..3
  const int ln = lane & 15;
  const int lq = lane >> 4;
  const int wm = wave >> 1;    // 0..1 : 128-row half
  const int wn = wave & 1;     // 0..1 : 64-col half

  // XCD swizzle: 1024 wgs = 8 XCD x 128. Per XCD: bn-slab of 4 tiles
  // (512 B-rows = 4 MB = one L2) x all 32 bm.
  const int bid = blockIdx.x;
  const int wg  = (bid & 7) * 128 + (bid >> 3);
  const int bm  = (wg & 31) * BM;
  const int bn  = (wg >> 5) * BN;

  // ---- staging inverse map: thread t -> (row-in-chunk, k-group) ----
  const int s_sw = (tid & 7) ^ ((tid >> 3) & 7);
  const int mrow = ((tid >> 3) << 1) + (s_sw >> 2);   // 0..63 within chunk
  const int k0   = (s_sw & 3) * 8;
  size_t aoff[4], boff[2];
#pragma unroll
  for (int c = 0; c < 4; ++c) aoff[c] = (size_t)(bm + c * 64 + mrow) * K_ + k0;
#pragma unroll
  for (int c = 0; c < 2; ++c) boff[c] = (size_t)(bn + c * 64 + mrow) * K_ + k0;

  auto stageA = [&](bf16_t* dst, int t) {   // 4 chunks of 64 rows
#pragma unroll
    for (int c = 0; c < 4; ++c)
      load_lds16(A + aoff[c] + (size_t)t * BK, dst + c * 2048 + tid * 8);
  };
  auto stageB = [&](bf16_t* dst, int t) {   // 2 chunks of 64 rows
#pragma unroll
    for (int c = 0; c < 2; ++c)
      load_lds16(B + boff[c] + (size_t)t * BK, dst + c * 2048 + tid * 8);
  };

  // ---- ds_read bases (swizzled) ----
  const int sw = ((((ln & 1) << 2) + lq) ^ (ln >> 1)) * 8;
  const int ra = wm * 4096 + (ln >> 1) * 64 + sw;   // af[i] at +i*512
  const int rb = wn * 2048 + (ln >> 1) * 64 + sw;   // bq[j] at +j*512

  f32x4 acc[8][4] = {};

  const bf16_t *pa0 = As, *pa1 = As + A_T, *pa2 = As + 2 * A_T;
  const bf16_t *pb0 = Bs, *pb1 = Bs + B_T, *pb2 = Bs + 2 * B_T;

  // prologue: stage tiles 0,1 (12 loads); retire tile0's 6, keep tile1's 6.
  stageA((bf16_t*)pa0, 0); stageB((bf16_t*)pb0, 0);
  stageA((bf16_t*)pa1, 1); stageB((bf16_t*)pb1, 1);
  asm volatile("s_waitcnt vmcnt(6)" ::: "memory");
  __builtin_amdgcn_s_barrier();

  for (int T = 0; T < NT; ++T) {
    bf16x8 af[8], bq[4];
    // ds_reads in consumption order: first MFMA needs af[0],bq[0] = reads 1,2.
    af[0] = *(const bf16x8*)(pa0 + ra);
#pragma unroll
    for (int j = 0; j < 4; ++j) bq[j] = *(const bf16x8*)(pb0 + rb + j * 512);
#pragma unroll
    for (int i = 1; i < 8; ++i) af[i] = *(const bf16x8*)(pa0 + ra + i * 512);

    if (T + 2 < NT) { stageA((bf16_t*)pa2, T + 2); stageB((bf16_t*)pb2, T + 2); }

#pragma unroll
    for (int i = 0; i < 8; ++i)
#pragma unroll
      for (int j = 0; j < 4; ++j)
        acc[i][j] = MFMA16(af[i], bq[j], acc[i][j]);

    if (T + 2 < NT) {
      asm volatile("s_waitcnt vmcnt(6)" ::: "memory");  // retires T+1's stage
    } else {
      asm volatile("s_waitcnt vmcnt(0)" ::: "memory");  // tail drain
    }
    asm volatile("s_waitcnt lgkmcnt(0)" ::: "memory");  // my reads done
    __builtin_amdgcn_s_barrier();

    const bf16_t* ta = pa0; pa0 = pa1; pa1 = pa2; pa2 = ta;
    const bf16_t* tb = pb0; pb0 = pb1; pb1 = pb2; pb2 = tb;
  }

  // epilogue: C/D layout col=lane&15, row=(lane>>4)*4+reg  [m89/m91 verified]
  // nt stores: C is write-once.
#pragma unroll
  for (int j = 0; j < 4; ++j) {
    const int col = bn + wn * 64 + j * 16 + ln;
    const float bv = bias[col];
#pragma unroll
    for (int i = 0; i < 8; ++i) {
      const int row0 = bm + wm * 128 + i * 16 + lq * 4;
      float* cp = C + (size_t)row0 * N_ + col;
#pragma unroll
      for (int r = 0; r < 4; ++r) {
        __builtin_nontemporal_store(acc[i][j][r] + bv, cp);
        cp += N_;
      }
    }
  }
}

extern "C" void kernel_launch(void* const* d_in, const int* in_sizes, int n_in,
                              void* d_out, int out_size, void* d_ws, size_t ws_size,
                              hipStream_t stream) {
  const float* x    = (const float*)d_in[0];  // [4,2048,4096] fp32
  const int*   qw   = (const int*)d_in[1];    // [4096,4096] int32 in [0,16)
  const float* sc   = (const float*)d_in[2];  // [4096,32] fp32
  const float* bias = (const float*)d_in[3];  // [4096] fp32
  float* out = (float*)d_out;                 // [8192,4096] fp32

  bf16_t* xb = (bf16_t*)d_ws;                 // M_*K_ bf16 = 64 MiB
  bf16_t* wb = xb + (size_t)M_ * K_;          // N_*K_ bf16 = 32 MiB

  cvt_x_kernel<<<(int)(((size_t)M_ * K_) / (256 * 8)), 256, 0, stream>>>(x, xb);
  dequant_kernel<<<(int)(((size_t)N_ * K_) / (256 * 8)), 256, 0, stream>>>(qw, sc, wb);

  const int nwg = (M_ / BM) * (N_ / BN);  // 32 * 32 = 1024 blocks, 2 per CU
  gemm_kernel<<<nwg, 256, 0, stream>>>(xb, wb, bias, out);
}

// Round 11
// 486.238 us; speedup vs baseline: 2.9531x; 1.1428x over previous
//
#include <hip/hip_runtime.h>
#include <hip/hip_bf16.h>

typedef __bf16 bf16_t;
typedef __bf16 bf16x8 __attribute__((ext_vector_type(8)));
typedef float  f32x4  __attribute__((ext_vector_type(4)));
typedef int    i32x4  __attribute__((ext_vector_type(4)));

static constexpr int M_ = 8192;   // 4 * 2048
static constexpr int N_ = 4096;   // out_f
static constexpr int K_ = 4096;   // in_f

// GEMM geometry: 256x256 tile, BK=32, 8 waves (2M x 4N) of 128x64 each.
// TRIPLE-buffered LDS (96 KB) -> stage T+2 while reading T -> counted
// vmcnt(4) and exactly ONE barrier per K-tile (vs 8 in the phase schedule).
static constexpr int BM = 256, BN = 256, BK = 32;
static constexpr int NT = K_ / BK;        // 128 K-tiles
static constexpr int A_T = BM * BK;       // 8192 elems = 16 KB per operand tile
static constexpr int B_T = BN * BK;       // 8192 elems = 16 KB

// async global->LDS, 16B per lane. LDS dest must be wave-uniform base + lane*16.
__device__ __forceinline__ void load_lds16(const bf16_t* g, bf16_t* l) {
  __builtin_amdgcn_global_load_lds(
      (const __attribute__((address_space(1))) void*)g,
      (__attribute__((address_space(3))) void*)l,
      16, 0, 0);
}

#define MFMA16(a, b, c) __builtin_amdgcn_mfma_f32_16x16x32_bf16((a), (b), (c), 0, 0, 0)

// ---- pass 1: x fp32 -> bf16 (nt loads: read-once) -------------------------
__global__ __launch_bounds__(256) void cvt_x_kernel(const float* __restrict__ x,
                                                    bf16_t* __restrict__ xb) {
  const size_t i = ((size_t)blockIdx.x * 256 + threadIdx.x) * 8;
  const f32x4 f0 = __builtin_nontemporal_load((const f32x4*)(x + i));
  const f32x4 f1 = __builtin_nontemporal_load((const f32x4*)(x + i + 4));
  bf16x8 o;
  o[0] = (bf16_t)f0[0]; o[1] = (bf16_t)f0[1]; o[2] = (bf16_t)f0[2]; o[3] = (bf16_t)f0[3];
  o[4] = (bf16_t)f1[0]; o[5] = (bf16_t)f1[1]; o[6] = (bf16_t)f1[2]; o[7] = (bf16_t)f1[3];
  *(bf16x8*)(xb + i) = o;   // cached store: gemm re-reads this soon
}

// ---- pass 2: W[o][i] = q[o][i] * scales[o][i/128] -> bf16 ----------------
__global__ __launch_bounds__(256) void dequant_kernel(const int* __restrict__ q,
                                                      const float* __restrict__ s,
                                                      bf16_t* __restrict__ wb) {
  const size_t base = ((size_t)blockIdx.x * 256 + threadIdx.x) * 8;
  const int o  = (int)(base >> 12);
  const int ii = (int)(base & 4095);
  const float sc = s[(o << 5) + (ii >> 7)];
  const i32x4 q0 = __builtin_nontemporal_load((const i32x4*)(q + base));
  const i32x4 q1 = __builtin_nontemporal_load((const i32x4*)(q + base + 4));
  bf16x8 w;
  w[0] = (bf16_t)((float)q0[0] * sc); w[1] = (bf16_t)((float)q0[1] * sc);
  w[2] = (bf16_t)((float)q0[2] * sc); w[3] = (bf16_t)((float)q0[3] * sc);
  w[4] = (bf16_t)((float)q1[0] * sc); w[5] = (bf16_t)((float)q1[1] * sc);
  w[6] = (bf16_t)((float)q1[2] * sc); w[7] = (bf16_t)((float)q1[3] * sc);
  *(bf16x8*)(wb + base) = w;  // cached store: gemm re-reads this soon
}

// ---- pass 3: C = A . B^T + bias ------------------------------------------
// LDS layout per tile (BK=32): row-pairs packed into 128-B lds-rows.
// Logical (m,k): elem = (m>>1)*64 + S*8 + (k&7), S = ((m&1)*4+(k>>3)) ^ ((m>>1)&7).
// Verified conflict-free in round 10 (SQ_LDS_BANK_CONFLICT = 0).
// Main loop per K-tile: 12 ds_reads (consumption order, compiler fine-grained
// lgkm) -> stage T+2 into 3rd buffer (4 gloads) -> 32 MFMA -> vmcnt(4)
// (retire T+1, keep T+2 in flight) -> lgkm(0) -> ONE barrier -> rotate.
__global__ __launch_bounds__(512, 2) void gemm_kernel(const bf16_t* __restrict__ A,
                                                      const bf16_t* __restrict__ B,
                                                      const float* __restrict__ bias,
                                                      float* __restrict__ C) {
  __shared__ __align__(16) bf16_t As[3 * A_T];  // 48 KiB
  __shared__ __align__(16) bf16_t Bs[3 * B_T];  // 48 KiB

  const int tid  = threadIdx.x;
  const int lane = tid & 63;
  const int wave = tid >> 6;
  const int ln = lane & 15;
  const int lq = lane >> 4;
  const int wm = wave >> 2;   // 0..1 : 128-row half
  const int wn = wave & 3;    // 0..3 : 64-col quarter

  // T1: XCD-bijective swizzle (512 wgs = 8 XCD x 64).
  const int bid = blockIdx.x;
  const int wg  = (bid & 7) * 64 + (bid >> 3);
  const int bn  = (wg & 15) * BN;
  const int bm  = (wg >> 4) * BM;

  // ---- staging inverse map (round-10, verified): thread t supplies the
  // global element for its linear LDS slot. u = (t&7)^((t>>3)&7):
  // row-in-chunk = 2*(t>>3)+(u>>2), k0 = (u&3)*8. Chunks of 128 rows.
  const int u    = (tid & 7) ^ ((tid >> 3) & 7);
  const int mrow = ((tid >> 3) << 1) + (u >> 2);   // 0..127 within chunk
  const int k0   = (u & 3) * 8;
  size_t aoff[2], boff[2];
#pragma unroll
  for (int c = 0; c < 2; ++c) {
    aoff[c] = (size_t)(bm + c * 128 + mrow) * K_ + k0;
    boff[c] = (size_t)(bn + c * 128 + mrow) * K_ + k0;
  }

  auto stageA = [&](bf16_t* dst, int t) {   // 2 chunks of 128 rows
#pragma unroll
    for (int c = 0; c < 2; ++c)
      load_lds16(A + aoff[c] + (size_t)t * BK, dst + c * 4096 + tid * 8);
  };
  auto stageB = [&](bf16_t* dst, int t) {
#pragma unroll
    for (int c = 0; c < 2; ++c)
      load_lds16(B + boff[c] + (size_t)t * BK, dst + c * 4096 + tid * 8);
  };

  // ---- ds_read bases (swizzled; round-10 verified conflict-free) ----
  const int sw = ((((ln & 1) << 2) + lq) ^ (ln >> 1)) * 8;
  const int ra = wm * 4096 + (ln >> 1) * 64 + sw;   // af[i] at +i*512
  const int rb = wn * 2048 + (ln >> 1) * 64 + sw;   // bq[j] at +j*512

  f32x4 acc[8][4] = {};

  const bf16_t *pa0 = As, *pa1 = As + A_T, *pa2 = As + 2 * A_T;
  const bf16_t *pb0 = Bs, *pb1 = Bs + B_T, *pb2 = Bs + 2 * B_T;

  // prologue: stage tiles 0,1 (8 loads); retire tile0's 4, keep tile1's 4.
  stageA((bf16_t*)pa0, 0); stageB((bf16_t*)pb0, 0);
  stageA((bf16_t*)pa1, 1); stageB((bf16_t*)pb1, 1);
  asm volatile("s_waitcnt vmcnt(4)" ::: "memory");
  __builtin_amdgcn_s_barrier();

  for (int T = 0; T < NT; ++T) {
    __builtin_amdgcn_sched_barrier(0);   // nothing floats above the tile start
    bf16x8 af[8], bq[4];
    // ds_reads in consumption order: first MFMA needs af[0], bq[0].
    af[0] = *(const bf16x8*)(pa0 + ra);
#pragma unroll
    for (int j = 0; j < 4; ++j) bq[j] = *(const bf16x8*)(pb0 + rb + j * 512);
#pragma unroll
    for (int i = 1; i < 8; ++i) af[i] = *(const bf16x8*)(pa0 + ra + i * 512);

    if (T + 2 < NT) { stageA((bf16_t*)pa2, T + 2); stageB((bf16_t*)pb2, T + 2); }

    __builtin_amdgcn_s_setprio(1);
#pragma unroll
    for (int i = 0; i < 8; ++i)
#pragma unroll
      for (int j = 0; j < 4; ++j)
        acc[i][j] = MFMA16(af[i], bq[j], acc[i][j]);
    __builtin_amdgcn_s_setprio(0);

    if (T + 2 < NT) {
      asm volatile("s_waitcnt vmcnt(4)" ::: "memory");  // T+1 resident; T+2 in flight
    } else {
      asm volatile("s_waitcnt vmcnt(0)" ::: "memory");  // tail drain
    }
    asm volatile("s_waitcnt lgkmcnt(0)" ::: "memory");  // my reads of pa0/pb0 done
    __builtin_amdgcn_s_barrier();                       // ONE barrier per K-tile

    const bf16_t* ta = pa0; pa0 = pa1; pa1 = pa2; pa2 = ta;
    const bf16_t* tb = pb0; pb0 = pb1; pb1 = pb2; pb2 = tb;
  }

  // epilogue: C/D layout col=lane&15, row=(lane>>4)*4+reg  [m89/m91 verified]
  // nt stores: C is write-once.
#pragma unroll
  for (int j = 0; j < 4; ++j) {
    const int col = bn + wn * 64 + j * 16 + ln;
    const float bv = bias[col];
#pragma unroll
    for (int i = 0; i < 8; ++i) {
      const int row0 = bm + wm * 128 + i * 16 + lq * 4;
      float* cp = C + (size_t)row0 * N_ + col;
#pragma unroll
      for (int r = 0; r < 4; ++r) {
        __builtin_nontemporal_store(acc[i][j][r] + bv, cp);
        cp += N_;
      }
    }
  }
}

extern "C" void kernel_launch(void* const* d_in, const int* in_sizes, int n_in,
                              void* d_out, int out_size, void* d_ws, size_t ws_size,
                              hipStream_t stream) {
  const float* x    = (const float*)d_in[0];  // [4,2048,4096] fp32
  const int*   qw   = (const int*)d_in[1];    // [4096,4096] int32 in [0,16)
  const float* sc   = (const float*)d_in[2];  // [4096,32] fp32
  const float* bias = (const float*)d_in[3];  // [4096] fp32
  float* out = (float*)d_out;                 // [8192,4096] fp32

  bf16_t* xb = (bf16_t*)d_ws;                 // M_*K_ bf16 = 64 MiB
  bf16_t* wb = xb + (size_t)M_ * K_;          // N_*K_ bf16 = 32 MiB

  cvt_x_kernel<<<(int)(((size_t)M_ * K_) / (256 * 8)), 256, 0, stream>>>(x, xb);
  dequant_kernel<<<(int)(((size_t)N_ * K_) / (256 * 8)), 256, 0, stream>>>(qw, sc, wb);

  const int nwg = (M_ / BM) * (N_ / BN);  // 32 * 16 = 512 blocks
  gemm_kernel<<<nwg, 512, 0, stream>>>(xb, wb, bias, out);
}